// Round 14
// baseline (173.934 us; speedup 1.0000x reference)
//
#include <hip/hip_runtime.h>
#include <hip/hip_bf16.h>

// ---------------------------------------------------------------------------
// Attention_58248346469030:  out = softmax((x@Wq)(x@Wk)^T * sc) @ (x@Wv) @ Wout + b
// B=4, S=2048, DIM=1024, INNER=1024 (full-dim attention, no head split).
//
// ALGEBRAIC FOLD (R10): dots = x@(sc*Wq@Wk^T)@x^T, out = (P@(x@(Wv@Wout)))/l + b
//   prep:  xh = fp16(x); WoutT = W_out^T fp16; prep_gemm64 (reads Wqkv f32
//          directly) -> Wyv [2048][1024] fp16
//   1) yv  = xh @ Wyv^T : y fp16 [8192][1024], v' bf16 -> VT[b][o][t]
//   2) P   = exp(y @ xh^T) bf16 + fused rowsum (shfl + atomicAdd — measured
//            cheaper than R13's ones-MFMA variant: +2us here vs +4.5us there)
//   3) out = (P @ VT^T)/rowsum + bias   fp32
//
// R12's T1 bijective XCD swizzle kept on all big GEMMs (FETCH 139->33MB).
// ---------------------------------------------------------------------------

typedef short    s16x8 __attribute__((ext_vector_type(8)));
typedef short    s16x4 __attribute__((ext_vector_type(4)));
typedef float    fx4   __attribute__((ext_vector_type(4)));
typedef _Float16 h16x8 __attribute__((ext_vector_type(8)));

__device__ __forceinline__ short f2bs(float f) {            // f32 -> bf16 bits (RNE)
  __hip_bfloat16 h = __float2bfloat16(f);
  short s; __builtin_memcpy(&s, &h, 2); return s;
}
__device__ __forceinline__ short f2hs(float f) {            // f32 -> fp16 bits (RNE)
  _Float16 h = (_Float16)f;
  short s; __builtin_memcpy(&s, &h, 2); return s;
}

__device__ __forceinline__ void gload16(const void* g, void* l) {
  __builtin_amdgcn_global_load_lds(
      (const __attribute__((address_space(1))) void*)g,
      (__attribute__((address_space(3))) void*)l, 16, 0, 0);
}

// T1: bijective XCD-chunked swizzle (grids all %8==0).
template<int GX, int GY>
__device__ __forceinline__ void xcd_map(int& bx, int& by, int& bz) {
  const int glin = ((int)blockIdx.z * GY + (int)blockIdx.y) * GX + (int)blockIdx.x;
  const int nwg  = GX * GY * (int)gridDim.z;
  const int s    = (glin & 7) * (nwg >> 3) + (glin >> 3);
  bx = s % GX;
  const int t = s / GX;
  by = t % GY;
  bz = t / GY;
}

// ---------------- prep kernels ----------------

__global__ void cvt_f32_f16(const float* __restrict__ in, short* __restrict__ out, int n4) {
  int i = blockIdx.x * blockDim.x + threadIdx.x;
  if (i < n4) {
    float4 v = reinterpret_cast<const float4*>(in)[i];
    s16x4 o;
    o.x = f2hs(v.x); o.y = f2hs(v.y); o.z = f2hs(v.z); o.w = f2hs(v.w);
    reinterpret_cast<s16x4*>(out)[i] = o;
  }
}

// WT[n][k] = W[k][n], fp16 out.
__global__ void transpose_w(const float* __restrict__ W, int K, int N,
                            short* __restrict__ WT) {
  __shared__ float tile[32][33];
  int k0 = blockIdx.y * 32, n0 = blockIdx.x * 32;
  int r = threadIdx.x >> 5, c = threadIdx.x & 31;
  for (int rr = r; rr < 32; rr += 8)
    tile[rr][c] = W[(size_t)(k0 + rr) * N + n0 + c];
  __syncthreads();
  for (int rr = r; rr < 32; rr += 8)
    WT[(size_t)(n0 + rr) * K + k0 + c] = f2hs(tile[c][rr]);
}

// Weight-fold GEMMs, 64x64 tiles, K=1024, fp16 MFMA. Reads Wqkv in f32
// (converted in-register during staging); A for the Wvo fold is WoutT fp16.
__global__ __launch_bounds__(256, 4)
void prep_gemm64(const float* __restrict__ Wqkv, const short* __restrict__ WoutT,
                 short* __restrict__ Wyv) {
  __shared__ __align__(16) short As[64 * 72];
  __shared__ __align__(16) short Bs[64 * 72];

  const bool isM = blockIdx.y < 16;
  const int arow0 = (blockIdx.y & 15) * 64;
  const int crow0 = arow0 + (isM ? 0 : 1024);
  const int bcol = blockIdx.x * 64;
  const float scale = isM ? 0.125f : 1.0f;

  const int t = threadIdx.x;
  const int r = t >> 2;
  const int sc = (t & 3) * 16;
  const float* Agf = Wqkv + (size_t)(arow0 + r) * 3072 + 1024 + sc;  // Wk f32
  const short* Agh = WoutT + (size_t)(arow0 + r) * 1024 + sc;        // WoutT fp16
  const float* Bgf = Wqkv + (size_t)(bcol + r) * 3072 + (isM ? 0 : 2048) + sc;

  short* Asw = &As[r * 72 + sc];
  short* Bsw = &Bs[r * 72 + sc];

  const int lane = t & 63;
  const int wid  = t >> 6;
  const int wm = wid >> 1, wn = wid & 1;
  const int fr = lane & 15, fg = lane >> 4;

  fx4 acc[2][2] = {};

  for (int kt = 0; kt < 1024; kt += 64) {
    s16x8 ar[2], br[2];
    if (isM) {
#pragma unroll
      for (int c = 0; c < 2; ++c) {
        float4 v0 = *reinterpret_cast<const float4*>(Agf + kt + c * 8);
        float4 v1 = *reinterpret_cast<const float4*>(Agf + kt + c * 8 + 4);
        ar[c][0] = f2hs(v0.x); ar[c][1] = f2hs(v0.y); ar[c][2] = f2hs(v0.z); ar[c][3] = f2hs(v0.w);
        ar[c][4] = f2hs(v1.x); ar[c][5] = f2hs(v1.y); ar[c][6] = f2hs(v1.z); ar[c][7] = f2hs(v1.w);
      }
    } else {
#pragma unroll
      for (int c = 0; c < 2; ++c)
        ar[c] = *reinterpret_cast<const s16x8*>(Agh + kt + c * 8);
    }
#pragma unroll
    for (int c = 0; c < 2; ++c) {
      float4 v0 = *reinterpret_cast<const float4*>(Bgf + kt + c * 8);
      float4 v1 = *reinterpret_cast<const float4*>(Bgf + kt + c * 8 + 4);
      br[c][0] = f2hs(v0.x); br[c][1] = f2hs(v0.y); br[c][2] = f2hs(v0.z); br[c][3] = f2hs(v0.w);
      br[c][4] = f2hs(v1.x); br[c][5] = f2hs(v1.y); br[c][6] = f2hs(v1.z); br[c][7] = f2hs(v1.w);
    }
    __syncthreads();
#pragma unroll
    for (int c = 0; c < 2; ++c) {
      *reinterpret_cast<s16x8*>(Asw + c * 8) = ar[c];
      *reinterpret_cast<s16x8*>(Bsw + c * 8) = br[c];
    }
    __syncthreads();
#pragma unroll
    for (int kk = 0; kk < 64; kk += 32) {
      s16x8 af[2], bf[2];
#pragma unroll
      for (int m = 0; m < 2; ++m)
        af[m] = *reinterpret_cast<const s16x8*>(&As[(wm * 32 + m * 16 + fr) * 72 + kk + fg * 8]);
#pragma unroll
      for (int n = 0; n < 2; ++n)
        bf[n] = *reinterpret_cast<const s16x8*>(&Bs[(wn * 32 + n * 16 + fr) * 72 + kk + fg * 8]);
#pragma unroll
      for (int m = 0; m < 2; ++m)
#pragma unroll
        for (int n = 0; n < 2; ++n)
          acc[m][n] = __builtin_amdgcn_mfma_f32_16x16x32_f16(
              __builtin_bit_cast(h16x8, af[m]), __builtin_bit_cast(h16x8, bf[n]),
              acc[m][n], 0, 0, 0);
    }
  }

  const int row0 = crow0 + wm * 32 + fg * 4;
  const int col0 = bcol + wn * 32 + fr;
#pragma unroll
  for (int m = 0; m < 2; ++m)
#pragma unroll
    for (int j = 0; j < 4; ++j) {
      const int row = row0 + m * 16 + j;
#pragma unroll
      for (int n = 0; n < 2; ++n)
        Wyv[(size_t)row * 1024 + col0 + n * 16] = f2hs(acc[m][n][j] * scale);
    }
}

// ---------------- 256x256 8-wave 4-slot ping-pong GEMM (R8 core + T1) ----------------
// C[M][N] = A[M][K] @ B'[N][K]^T
// EPI: 0 = yv write (cols <1024: y fp16; >=1024: v' bf16 -> VT=Cv2)
//      1 = exp -> bf16 + fused rowsum (shfl-reduce + atomicAdd into auxw)
template<int EPI, int DT, int GX, int GY>
__global__ __launch_bounds__(512, 2)
void gemm256(const short* __restrict__ A, int lda, long long bsA,
             const short* __restrict__ B, int ldb, long long bsB,
             void* __restrict__ Cv, int ldc, long long bsC,
             int K, short* __restrict__ Cv2, float* __restrict__ auxw) {
  __shared__ __align__(16) short S[4][16384];

  const int t = threadIdx.x;
  int bx, by, z;
  xcd_map<GX, GY>(bx, by, z);
  A += (size_t)z * bsA;
  B += (size_t)z * bsB;

  const int brow = by * 256;
  const int bcol = bx * 256;

  const int lane = t & 63;
  const int wid  = t >> 6;
  const int wm = wid >> 2;
  const int wn = wid & 3;
  const int fr = lane & 15;
  const int fg = lane >> 4;

  const int l2 = lane >> 2;
  const int gsrc = ((lane & 3) ^ ((lane >> 3) & 3)) * 8;
  const short* Ag0 = A + (size_t)(brow + wid * 32 + l2) * lda + gsrc;
  const short* Ag1 = Ag0 + (size_t)16 * lda;
  const short* Bg0 = B + (size_t)(bcol + wid * 32 + l2) * ldb + gsrc;
  const short* Bg1 = Bg0 + (size_t)16 * ldb;
  const int dA = wid * 1024;
  const int dB = 8192 + wid * 1024;

  const int gq = (fg ^ ((fr >> 1) & 3)) * 8;
  const int aB = (wm * 128 + fr) * 32 + gq;
  const int bB = 8192 + (wn * 64 + fr) * 32 + gq;

  fx4 acc[8][4] = {};
  s16x8 ra[2][8], rb[2][4];
  const int Km32 = K - 32;

  auto MM = [&](s16x8 av, s16x8 bv, fx4 c) -> fx4 {
    if constexpr (DT == 0)
      return __builtin_amdgcn_mfma_f32_16x16x32_f16(
          __builtin_bit_cast(h16x8, av), __builtin_bit_cast(h16x8, bv), c, 0, 0, 0);
    else
      return __builtin_amdgcn_mfma_f32_16x16x32_bf16(av, bv, c, 0, 0, 0);
  };

#pragma unroll
  for (int s = 0; s < 3; ++s) {
    const int kk = s * 32;
    gload16(Ag0 + kk, &S[s][dA]);
    gload16(Ag1 + kk, &S[s][dA + 512]);
    gload16(Bg0 + kk, &S[s][dB]);
    gload16(Bg1 + kk, &S[s][dB + 512]);
  }
  asm volatile("s_waitcnt vmcnt(8)" ::: "memory");
  __builtin_amdgcn_s_barrier();
#pragma unroll
  for (int m = 0; m < 8; ++m)
    ra[0][m] = *reinterpret_cast<const s16x8*>(&S[0][aB + m * 512]);
#pragma unroll
  for (int n = 0; n < 4; ++n)
    rb[0][n] = *reinterpret_cast<const s16x8*>(&S[0][bB + n * 512]);
  int knext = 96;

#define PHASE(SLOT, CUR, NXT)                                                \
  {                                                                          \
    asm volatile("s_waitcnt vmcnt(4)" ::: "memory");                         \
    __builtin_amdgcn_s_barrier();                                            \
    const int kk = knext <= Km32 ? knext : Km32;                             \
    short* D = &S[(SLOT + 3) & 3][0];                                        \
    gload16(Ag0 + kk, D + dA);                                               \
    gload16(Ag1 + kk, D + dA + 512);                                         \
    gload16(Bg0 + kk, D + dB);                                               \
    gload16(Bg1 + kk, D + dB + 512);                                         \
    knext += 32;                                                             \
    const short* Sl = &S[(SLOT + 1) & 3][0];                                 \
    _Pragma("unroll")                                                        \
    for (int m = 0; m < 8; ++m)                                              \
      ra[NXT][m] = *reinterpret_cast<const s16x8*>(&Sl[aB + m * 512]);       \
    _Pragma("unroll")                                                        \
    for (int n = 0; n < 4; ++n)                                              \
      rb[NXT][n] = *reinterpret_cast<const s16x8*>(&Sl[bB + n * 512]);       \
    __builtin_amdgcn_sched_barrier(0);                                       \
    __builtin_amdgcn_s_setprio(1);                                           \
    _Pragma("unroll")                                                        \
    for (int m = 0; m < 8; ++m)                                              \
      _Pragma("unroll")                                                      \
      for (int n = 0; n < 4; ++n)                                            \
        acc[m][n] = MM(ra[CUR][m], rb[CUR][n], acc[m][n]);                   \
    __builtin_amdgcn_s_setprio(0);                                           \
  }

  const int NPH = K >> 5;                // K multiple of 128 -> NPH % 4 == 0
  for (int p = 0; p < NPH; p += 4) {
    PHASE(0, 0, 1) PHASE(1, 1, 0) PHASE(2, 0, 1) PHASE(3, 1, 0)
  }
#undef PHASE
  asm volatile("s_waitcnt vmcnt(0)" ::: "memory");

  const int row0 = brow + wm * 128 + fg * 4;
  const int col0 = bcol + wn * 64 + fr;

  if constexpr (EPI == 0) {
    short* Cb = reinterpret_cast<short*>(Cv);
    if (bcol < 1024) {                    // y columns -> fp16 [8192][1024]
#pragma unroll
      for (int m = 0; m < 8; ++m)
#pragma unroll
        for (int j = 0; j < 4; ++j) {
          const int row = row0 + m * 16 + j;
#pragma unroll
          for (int n = 0; n < 4; ++n)
            Cb[(size_t)row * ldc + col0 + n * 16] = f2hs(acc[m][n][j]);
        }
    } else {                              // v' columns -> bf16 into VT[b][o][t]
#pragma unroll
      for (int m = 0; m < 8; ++m)
#pragma unroll
        for (int j = 0; j < 4; ++j) {
          const int row = row0 + m * 16 + j;
          const int zb = row >> 11, s = row & 2047;
#pragma unroll
          for (int n = 0; n < 4; ++n) {
            const int d = col0 + n * 16 - 1024;
            Cv2[((size_t)(zb << 10) + d) * 2048 + s] = f2bs(acc[m][n][j]);
          }
        }
    }
  } else {
    // P = exp(dots) bf16; fused row-sum: 4 vals/lane over 16-lane fr-group
    // (64 cols/wave), shfl-xor reduce, 1 atomicAdd per (row, wave).
    short* Cb = reinterpret_cast<short*>(Cv) + (size_t)z * bsC;
    float* rs_out = auxw + (size_t)z * 2048;
#pragma unroll
    for (int m = 0; m < 8; ++m)
#pragma unroll
      for (int j = 0; j < 4; ++j) {
        const int row = row0 + m * 16 + j;
        float e[4];
#pragma unroll
        for (int n = 0; n < 4; ++n) {
          e[n] = exp2f(acc[m][n][j] * 1.4426950408889634f);
          Cb[(size_t)row * ldc + col0 + n * 16] = f2bs(e[n]);
        }
        float ps = (e[0] + e[1]) + (e[2] + e[3]);
        ps += __shfl_xor(ps, 1);
        ps += __shfl_xor(ps, 2);
        ps += __shfl_xor(ps, 4);
        ps += __shfl_xor(ps, 8);
        if (fr == 0) atomicAdd(&rs_out[row], ps);
      }
  }
}

// ---------------- 128x128 R1-core GEMM (out; /rowsum + bias) ----------------
__global__ __launch_bounds__(256, 2)
void gemm_out(const short* __restrict__ A, int lda, long long bsA,
              const short* __restrict__ B, int ldb, long long bsB,
              float* __restrict__ Cv, int ldc, long long bsC,
              int K, const float* __restrict__ aux, const float* __restrict__ auxw) {
  __shared__ __align__(16) short As[128 * 72];
  __shared__ __align__(16) short Bs[128 * 72];

  const int t = threadIdx.x;
  int bx, by, z;
  xcd_map<8, 16>(bx, by, z);
  A += (size_t)z * bsA;
  B += (size_t)z * bsB;

  const int brow = by * 128;
  const int bcol = bx * 128;

  const int srow = t >> 1;
  const int scol = (t & 1) << 5;
  const short* Ag = A + (size_t)(brow + srow) * lda + scol;
  const short* Bg = B + (size_t)(bcol + srow) * ldb + scol;
  short* Asw = &As[srow * 72 + scol];
  short* Bsw = &Bs[srow * 72 + scol];

  const int lane = t & 63;
  const int wid  = t >> 6;
  const int wr = (wid >> 1) * 64;
  const int wc = (wid & 1) * 64;
  const int fr = lane & 15;
  const int fg = lane >> 4;

  fx4 acc[4][4] = {};

  for (int kt = 0; kt < K; kt += 64) {
    s16x8 ar[4], br[4];
#pragma unroll
    for (int c = 0; c < 4; ++c) ar[c] = *reinterpret_cast<const s16x8*>(Ag + kt + c * 8);
#pragma unroll
    for (int c = 0; c < 4; ++c) br[c] = *reinterpret_cast<const s16x8*>(Bg + kt + c * 8);
    __syncthreads();
#pragma unroll
    for (int c = 0; c < 4; ++c) *reinterpret_cast<s16x8*>(Asw + c * 8) = ar[c];
#pragma unroll
    for (int c = 0; c < 4; ++c) *reinterpret_cast<s16x8*>(Bsw + c * 8) = br[c];
    __syncthreads();

#pragma unroll
    for (int kk = 0; kk < 64; kk += 32) {
      s16x8 af[4], bfv[4];
#pragma unroll
      for (int m = 0; m < 4; ++m)
        af[m] = *reinterpret_cast<const s16x8*>(&As[(wr + m * 16 + fr) * 72 + kk + fg * 8]);
#pragma unroll
      for (int n = 0; n < 4; ++n)
        bfv[n] = *reinterpret_cast<const s16x8*>(&Bs[(wc + n * 16 + fr) * 72 + kk + fg * 8]);
#pragma unroll
      for (int m = 0; m < 4; ++m)
#pragma unroll
        for (int n = 0; n < 4; ++n)
          acc[m][n] = __builtin_amdgcn_mfma_f32_16x16x32_bf16(af[m], bfv[n], acc[m][n], 0, 0, 0);
    }
  }

  const int row0 = brow + wr + fg * 4;
  const int col0 = bcol + wc + fr;
  const float* rs_in = auxw + (size_t)z * 2048;
#pragma unroll
  for (int m = 0; m < 4; ++m)
#pragma unroll
    for (int j = 0; j < 4; ++j) {
      const int row = row0 + m * 16 + j;
      const float rcp = 1.0f / rs_in[row];
#pragma unroll
      for (int n = 0; n < 4; ++n) {
        const int col = col0 + n * 16;
        Cv[(size_t)z * bsC + (size_t)row * ldc + col] = acc[m][n][j] * rcp + aux[col];
      }
    }
}

// ---------------- launch ----------------

extern "C" void kernel_launch(void* const* d_in, const int* in_sizes, int n_in,
                              void* d_out, int out_size, void* d_ws, size_t ws_size,
                              hipStream_t stream) {
  const float* x    = (const float*)d_in[0];   // [4,2048,1024]
  const float* Wqkv = (const float*)d_in[1];   // [1024,3072]
  const float* Wout = (const float*)d_in[2];   // [1024,1024]
  const float* bout = (const float*)d_in[3];   // [1024]
  float* out = (float*)d_out;                  // [4,2048,1024] fp32

  // workspace layout (bytes)
  char* ws = (char*)d_ws;
  short* xh    = (short*)(ws + 0);             //  16777216  fp16 x [8192][1024]
  short* WoutT = (short*)(ws + 16777216);      //   2097152  fp16 W_out^T [1024][1024]
  short* Wyv   = (short*)(ws + 18874368);      //   4194304  fp16 [M^T; Wvo^T] [2048][1024]
  short* y     = (short*)(ws + 23068672);      //  16777216  fp16 [8192][1024]
  short* VT    = (short*)(ws + 39845888);      //  16777216  bf16 v' [4][1024][2048]
  short* P     = (short*)(ws + 56623104);      //  33554432  bf16 [4][2048][2048]
  float* rsum  = (float*)(ws + 90177536);      //     32768  [4][2048]
  if (ws_size < 90210304) return;              // insufficient scratch -> visible failure

  hipMemsetAsync(rsum, 0, 8192 * sizeof(float), stream);
  cvt_f32_f16<<<8192, 256, 0, stream>>>(x, xh, 8388608 / 4);
  transpose_w<<<dim3(32, 32), 256, 0, stream>>>(Wout, 1024, 1024, WoutT);
  // M^T (scale folded) and Wvo^T -> Wyv (reads Wqkv f32 directly)
  prep_gemm64<<<dim3(16, 32), 256, 0, stream>>>(Wqkv, WoutT, Wyv);

  // yv = xh @ Wyv^T  (y cols 0-1023 -> y; v' -> VT)           256 blocks (1/CU)
  gemm256<0, 0, 8, 32><<<dim3(8, 32, 1), 512, 0, stream>>>(
      xh, 1024, 0, Wyv, 1024, 0, y, 1024, 0, 1024, VT, nullptr);
  // P = exp(y @ xh^T) + fused rowsum                          256 blocks (1/CU)
  gemm256<1, 0, 8, 8><<<dim3(8, 8, 4), 512, 0, stream>>>(
      y, 1024, 2048LL * 1024, xh, 1024, 2048LL * 1024,
      P, 2048, 2048LL * 2048, 1024, nullptr, rsum);
  // out = (P @ VT^T)/rowsum + bias                            512 blocks (2/CU)
  gemm_out<<<dim3(8, 16, 4), 256, 0, stream>>>(
      P, 2048, 2048LL * 2048, VT, 2048, 1024LL * 2048,
      out, 1024, 2048LL * 1024, 2048, bout, rsum);
}

// Round 15
// 169.173 us; speedup vs baseline: 1.0281x; 1.0281x over previous
//
#include <hip/hip_runtime.h>
#include <hip/hip_bf16.h>

// ---------------------------------------------------------------------------
// Attention_58248346469030:  out = softmax((x@Wq)(x@Wk)^T * sc) @ (x@Wv) @ Wout + b
// B=4, S=2048, DIM=1024, INNER=1024 (full-dim attention, no head split).
//
// ALGEBRAIC FOLD (R10): dots = x@(sc*Wq@Wk^T)@x^T, out = (P@(x@(Wv@Wout)))/l + b
//   prep:  xh = fp16(x); WoutT = W_out^T fp16; prep_gemm64 (reads Wqkv f32
//          directly) -> Wyv [2048][1024] fp16
//   1) yv  = xh @ Wyv^T : y fp16 [8192][1024], v' bf16 -> VT[b][o][t]
//   2) P   = exp(y @ xh^T)  bf16  (pure store epilogue)
//   3) out = (P @ VT^T)/rowsum + bias, rowsum computed IN gemm_out on the
//      VALU pipe (bf16 bit-ops on the A=P fragments; VALUBusy was 9.5%, MFMA
//      and VALU overlap) — replaces R13's ones-MFMA (+25% MFMA ops, +4.5us)
//      and R12/R14's atomicAdd epilogue (+7..14us).
//
// T1 bijective XCD swizzle kept on all big GEMMs (FETCH 139->33MB).
// ---------------------------------------------------------------------------

typedef short    s16x8 __attribute__((ext_vector_type(8)));
typedef short    s16x4 __attribute__((ext_vector_type(4)));
typedef float    fx4   __attribute__((ext_vector_type(4)));
typedef unsigned ux4   __attribute__((ext_vector_type(4)));
typedef _Float16 h16x8 __attribute__((ext_vector_type(8)));

__device__ __forceinline__ short f2bs(float f) {            // f32 -> bf16 bits (RNE)
  __hip_bfloat16 h = __float2bfloat16(f);
  short s; __builtin_memcpy(&s, &h, 2); return s;
}
__device__ __forceinline__ short f2hs(float f) {            // f32 -> fp16 bits (RNE)
  _Float16 h = (_Float16)f;
  short s; __builtin_memcpy(&s, &h, 2); return s;
}

__device__ __forceinline__ void gload16(const void* g, void* l) {
  __builtin_amdgcn_global_load_lds(
      (const __attribute__((address_space(1))) void*)g,
      (__attribute__((address_space(3))) void*)l, 16, 0, 0);
}

// T1: bijective XCD-chunked swizzle (grids all %8==0).
template<int GX, int GY>
__device__ __forceinline__ void xcd_map(int& bx, int& by, int& bz) {
  const int glin = ((int)blockIdx.z * GY + (int)blockIdx.y) * GX + (int)blockIdx.x;
  const int nwg  = GX * GY * (int)gridDim.z;
  const int s    = (glin & 7) * (nwg >> 3) + (glin >> 3);
  bx = s % GX;
  const int t = s / GX;
  by = t % GY;
  bz = t / GY;
}

// ---------------- prep kernels ----------------

__global__ void cvt_f32_f16(const float* __restrict__ in, short* __restrict__ out, int n4) {
  int i = blockIdx.x * blockDim.x + threadIdx.x;
  if (i < n4) {
    float4 v = reinterpret_cast<const float4*>(in)[i];
    s16x4 o;
    o.x = f2hs(v.x); o.y = f2hs(v.y); o.z = f2hs(v.z); o.w = f2hs(v.w);
    reinterpret_cast<s16x4*>(out)[i] = o;
  }
}

// WT[n][k] = W[k][n], fp16 out.
__global__ void transpose_w(const float* __restrict__ W, int K, int N,
                            short* __restrict__ WT) {
  __shared__ float tile[32][33];
  int k0 = blockIdx.y * 32, n0 = blockIdx.x * 32;
  int r = threadIdx.x >> 5, c = threadIdx.x & 31;
  for (int rr = r; rr < 32; rr += 8)
    tile[rr][c] = W[(size_t)(k0 + rr) * N + n0 + c];
  __syncthreads();
  for (int rr = r; rr < 32; rr += 8)
    WT[(size_t)(n0 + rr) * K + k0 + c] = f2hs(tile[c][rr]);
}

// Weight-fold GEMMs, 64x64 tiles, K=1024, fp16 MFMA. Reads Wqkv in f32
// (converted in-register during staging); A for the Wvo fold is WoutT fp16.
__global__ __launch_bounds__(256, 4)
void prep_gemm64(const float* __restrict__ Wqkv, const short* __restrict__ WoutT,
                 short* __restrict__ Wyv) {
  __shared__ __align__(16) short As[64 * 72];
  __shared__ __align__(16) short Bs[64 * 72];

  const bool isM = blockIdx.y < 16;
  const int arow0 = (blockIdx.y & 15) * 64;
  const int crow0 = arow0 + (isM ? 0 : 1024);
  const int bcol = blockIdx.x * 64;
  const float scale = isM ? 0.125f : 1.0f;

  const int t = threadIdx.x;
  const int r = t >> 2;
  const int sc = (t & 3) * 16;
  const float* Agf = Wqkv + (size_t)(arow0 + r) * 3072 + 1024 + sc;  // Wk f32
  const short* Agh = WoutT + (size_t)(arow0 + r) * 1024 + sc;        // WoutT fp16
  const float* Bgf = Wqkv + (size_t)(bcol + r) * 3072 + (isM ? 0 : 2048) + sc;

  short* Asw = &As[r * 72 + sc];
  short* Bsw = &Bs[r * 72 + sc];

  const int lane = t & 63;
  const int wid  = t >> 6;
  const int wm = wid >> 1, wn = wid & 1;
  const int fr = lane & 15, fg = lane >> 4;

  fx4 acc[2][2] = {};

  for (int kt = 0; kt < 1024; kt += 64) {
    s16x8 ar[2], br[2];
    if (isM) {
#pragma unroll
      for (int c = 0; c < 2; ++c) {
        float4 v0 = *reinterpret_cast<const float4*>(Agf + kt + c * 8);
        float4 v1 = *reinterpret_cast<const float4*>(Agf + kt + c * 8 + 4);
        ar[c][0] = f2hs(v0.x); ar[c][1] = f2hs(v0.y); ar[c][2] = f2hs(v0.z); ar[c][3] = f2hs(v0.w);
        ar[c][4] = f2hs(v1.x); ar[c][5] = f2hs(v1.y); ar[c][6] = f2hs(v1.z); ar[c][7] = f2hs(v1.w);
      }
    } else {
#pragma unroll
      for (int c = 0; c < 2; ++c)
        ar[c] = *reinterpret_cast<const s16x8*>(Agh + kt + c * 8);
    }
#pragma unroll
    for (int c = 0; c < 2; ++c) {
      float4 v0 = *reinterpret_cast<const float4*>(Bgf + kt + c * 8);
      float4 v1 = *reinterpret_cast<const float4*>(Bgf + kt + c * 8 + 4);
      br[c][0] = f2hs(v0.x); br[c][1] = f2hs(v0.y); br[c][2] = f2hs(v0.z); br[c][3] = f2hs(v0.w);
      br[c][4] = f2hs(v1.x); br[c][5] = f2hs(v1.y); br[c][6] = f2hs(v1.z); br[c][7] = f2hs(v1.w);
    }
    __syncthreads();
#pragma unroll
    for (int c = 0; c < 2; ++c) {
      *reinterpret_cast<s16x8*>(Asw + c * 8) = ar[c];
      *reinterpret_cast<s16x8*>(Bsw + c * 8) = br[c];
    }
    __syncthreads();
#pragma unroll
    for (int kk = 0; kk < 64; kk += 32) {
      s16x8 af[2], bf[2];
#pragma unroll
      for (int m = 0; m < 2; ++m)
        af[m] = *reinterpret_cast<const s16x8*>(&As[(wm * 32 + m * 16 + fr) * 72 + kk + fg * 8]);
#pragma unroll
      for (int n = 0; n < 2; ++n)
        bf[n] = *reinterpret_cast<const s16x8*>(&Bs[(wn * 32 + n * 16 + fr) * 72 + kk + fg * 8]);
#pragma unroll
      for (int m = 0; m < 2; ++m)
#pragma unroll
        for (int n = 0; n < 2; ++n)
          acc[m][n] = __builtin_amdgcn_mfma_f32_16x16x32_f16(
              __builtin_bit_cast(h16x8, af[m]), __builtin_bit_cast(h16x8, bf[n]),
              acc[m][n], 0, 0, 0);
    }
  }

  const int row0 = crow0 + wm * 32 + fg * 4;
  const int col0 = bcol + wn * 32 + fr;
#pragma unroll
  for (int m = 0; m < 2; ++m)
#pragma unroll
    for (int j = 0; j < 4; ++j) {
      const int row = row0 + m * 16 + j;
#pragma unroll
      for (int n = 0; n < 2; ++n)
        Wyv[(size_t)row * 1024 + col0 + n * 16] = f2hs(acc[m][n][j] * scale);
    }
}

// ---------------- 256x256 8-wave 4-slot ping-pong GEMM (R8 core + T1) ----------------
// C[M][N] = A[M][K] @ B'[N][K]^T
// EPI: 0 = yv write (cols <1024: y fp16; >=1024: v' bf16 -> VT=Cv2)
//      1 = exp -> bf16 (pure store)
template<int EPI, int DT, int GX, int GY>
__global__ __launch_bounds__(512, 2)
void gemm256(const short* __restrict__ A, int lda, long long bsA,
             const short* __restrict__ B, int ldb, long long bsB,
             void* __restrict__ Cv, int ldc, long long bsC,
             int K, short* __restrict__ Cv2) {
  __shared__ __align__(16) short S[4][16384];

  const int t = threadIdx.x;
  int bx, by, z;
  xcd_map<GX, GY>(bx, by, z);
  A += (size_t)z * bsA;
  B += (size_t)z * bsB;

  const int brow = by * 256;
  const int bcol = bx * 256;

  const int lane = t & 63;
  const int wid  = t >> 6;
  const int wm = wid >> 2;
  const int wn = wid & 3;
  const int fr = lane & 15;
  const int fg = lane >> 4;

  const int l2 = lane >> 2;
  const int gsrc = ((lane & 3) ^ ((lane >> 3) & 3)) * 8;
  const short* Ag0 = A + (size_t)(brow + wid * 32 + l2) * lda + gsrc;
  const short* Ag1 = Ag0 + (size_t)16 * lda;
  const short* Bg0 = B + (size_t)(bcol + wid * 32 + l2) * ldb + gsrc;
  const short* Bg1 = Bg0 + (size_t)16 * ldb;
  const int dA = wid * 1024;
  const int dB = 8192 + wid * 1024;

  const int gq = (fg ^ ((fr >> 1) & 3)) * 8;
  const int aB = (wm * 128 + fr) * 32 + gq;
  const int bB = 8192 + (wn * 64 + fr) * 32 + gq;

  fx4 acc[8][4] = {};
  s16x8 ra[2][8], rb[2][4];
  const int Km32 = K - 32;

  auto MM = [&](s16x8 av, s16x8 bv, fx4 c) -> fx4 {
    if constexpr (DT == 0)
      return __builtin_amdgcn_mfma_f32_16x16x32_f16(
          __builtin_bit_cast(h16x8, av), __builtin_bit_cast(h16x8, bv), c, 0, 0, 0);
    else
      return __builtin_amdgcn_mfma_f32_16x16x32_bf16(av, bv, c, 0, 0, 0);
  };

#pragma unroll
  for (int s = 0; s < 3; ++s) {
    const int kk = s * 32;
    gload16(Ag0 + kk, &S[s][dA]);
    gload16(Ag1 + kk, &S[s][dA + 512]);
    gload16(Bg0 + kk, &S[s][dB]);
    gload16(Bg1 + kk, &S[s][dB + 512]);
  }
  asm volatile("s_waitcnt vmcnt(8)" ::: "memory");
  __builtin_amdgcn_s_barrier();
#pragma unroll
  for (int m = 0; m < 8; ++m)
    ra[0][m] = *reinterpret_cast<const s16x8*>(&S[0][aB + m * 512]);
#pragma unroll
  for (int n = 0; n < 4; ++n)
    rb[0][n] = *reinterpret_cast<const s16x8*>(&S[0][bB + n * 512]);
  int knext = 96;

#define PHASE(SLOT, CUR, NXT)                                                \
  {                                                                          \
    asm volatile("s_waitcnt vmcnt(4)" ::: "memory");                         \
    __builtin_amdgcn_s_barrier();                                            \
    const int kk = knext <= Km32 ? knext : Km32;                             \
    short* D = &S[(SLOT + 3) & 3][0];                                        \
    gload16(Ag0 + kk, D + dA);                                               \
    gload16(Ag1 + kk, D + dA + 512);                                         \
    gload16(Bg0 + kk, D + dB);                                               \
    gload16(Bg1 + kk, D + dB + 512);                                         \
    knext += 32;                                                             \
    const short* Sl = &S[(SLOT + 1) & 3][0];                                 \
    _Pragma("unroll")                                                        \
    for (int m = 0; m < 8; ++m)                                              \
      ra[NXT][m] = *reinterpret_cast<const s16x8*>(&Sl[aB + m * 512]);       \
    _Pragma("unroll")                                                        \
    for (int n = 0; n < 4; ++n)                                              \
      rb[NXT][n] = *reinterpret_cast<const s16x8*>(&Sl[bB + n * 512]);       \
    __builtin_amdgcn_sched_barrier(0);                                       \
    __builtin_amdgcn_s_setprio(1);                                           \
    _Pragma("unroll")                                                        \
    for (int m = 0; m < 8; ++m)                                              \
      _Pragma("unroll")                                                      \
      for (int n = 0; n < 4; ++n)                                            \
        acc[m][n] = MM(ra[CUR][m], rb[CUR][n], acc[m][n]);                   \
    __builtin_amdgcn_s_setprio(0);                                           \
  }

  const int NPH = K >> 5;                // K multiple of 128 -> NPH % 4 == 0
  for (int p = 0; p < NPH; p += 4) {
    PHASE(0, 0, 1) PHASE(1, 1, 0) PHASE(2, 0, 1) PHASE(3, 1, 0)
  }
#undef PHASE
  asm volatile("s_waitcnt vmcnt(0)" ::: "memory");

  const int row0 = brow + wm * 128 + fg * 4;
  const int col0 = bcol + wn * 64 + fr;

  if constexpr (EPI == 0) {
    short* Cb = reinterpret_cast<short*>(Cv);
    if (bcol < 1024) {                    // y columns -> fp16 [8192][1024]
#pragma unroll
      for (int m = 0; m < 8; ++m)
#pragma unroll
        for (int j = 0; j < 4; ++j) {
          const int row = row0 + m * 16 + j;
#pragma unroll
          for (int n = 0; n < 4; ++n)
            Cb[(size_t)row * ldc + col0 + n * 16] = f2hs(acc[m][n][j]);
        }
    } else {                              // v' columns -> bf16 into VT[b][o][t]
#pragma unroll
      for (int m = 0; m < 8; ++m)
#pragma unroll
        for (int j = 0; j < 4; ++j) {
          const int row = row0 + m * 16 + j;
          const int zb = row >> 11, s = row & 2047;
#pragma unroll
          for (int n = 0; n < 4; ++n) {
            const int d = col0 + n * 16 - 1024;
            Cv2[((size_t)(zb << 10) + d) * 2048 + s] = f2bs(acc[m][n][j]);
          }
        }
    }
  } else {
    // P = exp(dots) bf16, pure store (rowsum computed in gemm_out on VALU)
    short* Cb = reinterpret_cast<short*>(Cv) + (size_t)z * bsC;
#pragma unroll
    for (int m = 0; m < 8; ++m)
#pragma unroll
      for (int j = 0; j < 4; ++j) {
        const int row = row0 + m * 16 + j;
#pragma unroll
        for (int n = 0; n < 4; ++n)
          Cb[(size_t)row * ldc + col0 + n * 16] =
              f2bs(exp2f(acc[m][n][j] * 1.4426950408889634f));
      }
  }
}

// ---------------- 128x128 R1-core GEMM (out; VALU-pipe rowsum) ----------------
// Rowsum of P over K (the softmax axis) accumulates on the VALU from the
// A-fragments (bf16 bit-extract + f32 add); MFMA count stays at baseline.
__global__ __launch_bounds__(256, 2)
void gemm_out(const short* __restrict__ A, int lda, long long bsA,
              const short* __restrict__ B, int ldb, long long bsB,
              float* __restrict__ Cv, int ldc, long long bsC,
              int K, const float* __restrict__ aux) {
  __shared__ __align__(16) short As[128 * 72];
  __shared__ __align__(16) short Bs[128 * 72];

  const int t = threadIdx.x;
  int bx, by, z;
  xcd_map<8, 16>(bx, by, z);
  A += (size_t)z * bsA;
  B += (size_t)z * bsB;

  const int brow = by * 128;
  const int bcol = bx * 128;

  const int srow = t >> 1;
  const int scol = (t & 1) << 5;
  const short* Ag = A + (size_t)(brow + srow) * lda + scol;
  const short* Bg = B + (size_t)(bcol + srow) * ldb + scol;
  short* Asw = &As[srow * 72 + scol];
  short* Bsw = &Bs[srow * 72 + scol];

  const int lane = t & 63;
  const int wid  = t >> 6;
  const int wr = (wid >> 1) * 64;
  const int wc = (wid & 1) * 64;
  const int fr = lane & 15;
  const int fg = lane >> 4;

  fx4 acc[4][4] = {};
  float rs[4] = {0.f, 0.f, 0.f, 0.f};    // per-lane partial rowsum of row wr+m*16+fr

  for (int kt = 0; kt < K; kt += 64) {
    s16x8 ar[4], br[4];
#pragma unroll
    for (int c = 0; c < 4; ++c) ar[c] = *reinterpret_cast<const s16x8*>(Ag + kt + c * 8);
#pragma unroll
    for (int c = 0; c < 4; ++c) br[c] = *reinterpret_cast<const s16x8*>(Bg + kt + c * 8);
    __syncthreads();
#pragma unroll
    for (int c = 0; c < 4; ++c) *reinterpret_cast<s16x8*>(Asw + c * 8) = ar[c];
#pragma unroll
    for (int c = 0; c < 4; ++c) *reinterpret_cast<s16x8*>(Bsw + c * 8) = br[c];
    __syncthreads();

#pragma unroll
    for (int kk = 0; kk < 64; kk += 32) {
      s16x8 af[4], bfv[4];
#pragma unroll
      for (int m = 0; m < 4; ++m)
        af[m] = *reinterpret_cast<const s16x8*>(&As[(wr + m * 16 + fr) * 72 + kk + fg * 8]);
#pragma unroll
      for (int n = 0; n < 4; ++n)
        bfv[n] = *reinterpret_cast<const s16x8*>(&Bs[(wc + n * 16 + fr) * 72 + kk + fg * 8]);
#pragma unroll
      for (int m = 0; m < 4; ++m) {
#pragma unroll
        for (int n = 0; n < 4; ++n)
          acc[m][n] = __builtin_amdgcn_mfma_f32_16x16x32_bf16(af[m], bfv[n], acc[m][n], 0, 0, 0);
        // VALU rowsum: af[m] = 8 bf16 of P row (wr+m*16+fr), k-slice fg*8+kk..+7
        ux4 w = __builtin_bit_cast(ux4, af[m]);
#pragma unroll
        for (int i = 0; i < 4; ++i) {
          const unsigned lo = w[i] << 16;
          const unsigned hi = w[i] & 0xffff0000u;
          rs[m] += __builtin_bit_cast(float, lo) + __builtin_bit_cast(float, hi);
        }
      }
    }
  }

  // complete rowsums: reduce across the 4 k-slice lanes (same fr, fg 0..3)
#pragma unroll
  for (int m = 0; m < 4; ++m) {
    rs[m] += __shfl_xor(rs[m], 16);
    rs[m] += __shfl_xor(rs[m], 32);
  }

  // D layout: row = fg*4 + j, col = fr. Rowsum for row fg*4+j lives at the
  // lane whose fr == fg*4+j (any fg copy; lane fg*4+j itself has it).
  const int row0 = brow + wr + fg * 4;
  const int col0 = bcol + wc + fr;
#pragma unroll
  for (int m = 0; m < 4; ++m)
#pragma unroll
    for (int j = 0; j < 4; ++j) {
      const int row = row0 + m * 16 + j;
      const float rcp = 1.0f / __shfl(rs[m], fg * 4 + j);
#pragma unroll
      for (int n = 0; n < 4; ++n) {
        const int col = col0 + n * 16;
        Cv[(size_t)z * bsC + (size_t)row * ldc + col] = acc[m][n][j] * rcp + aux[col];
      }
    }
}

// ---------------- launch ----------------

extern "C" void kernel_launch(void* const* d_in, const int* in_sizes, int n_in,
                              void* d_out, int out_size, void* d_ws, size_t ws_size,
                              hipStream_t stream) {
  const float* x    = (const float*)d_in[0];   // [4,2048,1024]
  const float* Wqkv = (const float*)d_in[1];   // [1024,3072]
  const float* Wout = (const float*)d_in[2];   // [1024,1024]
  const float* bout = (const float*)d_in[3];   // [1024]
  float* out = (float*)d_out;                  // [4,2048,1024] fp32

  // workspace layout (bytes)
  char* ws = (char*)d_ws;
  short* xh    = (short*)(ws + 0);             //  16777216  fp16 x [8192][1024]
  short* WoutT = (short*)(ws + 16777216);      //   2097152  fp16 W_out^T [1024][1024]
  short* Wyv   = (short*)(ws + 18874368);      //   4194304  fp16 [M^T; Wvo^T] [2048][1024]
  short* y     = (short*)(ws + 23068672);      //  16777216  fp16 [8192][1024]
  short* VT    = (short*)(ws + 39845888);      //  16777216  bf16 v' [4][1024][2048]
  short* P     = (short*)(ws + 56623104);      //  33554432  bf16 [4][2048][2048]
  if (ws_size < 90177536) return;              // insufficient scratch -> visible failure

  cvt_f32_f16<<<8192, 256, 0, stream>>>(x, xh, 8388608 / 4);
  transpose_w<<<dim3(32, 32), 256, 0, stream>>>(Wout, 1024, 1024, WoutT);
  // M^T (scale folded) and Wvo^T -> Wyv (reads Wqkv f32 directly)
  prep_gemm64<<<dim3(16, 32), 256, 0, stream>>>(Wqkv, WoutT, Wyv);

  // yv = xh @ Wyv^T  (y cols 0-1023 -> y; v' -> VT)           256 blocks (1/CU)
  gemm256<0, 0, 8, 32><<<dim3(8, 32, 1), 512, 0, stream>>>(
      xh, 1024, 0, Wyv, 1024, 0, y, 1024, 0, 1024, VT);
  // P = exp(y @ xh^T)                                          256 blocks (1/CU)
  gemm256<1, 0, 8, 8><<<dim3(8, 8, 4), 512, 0, stream>>>(
      y, 1024, 2048LL * 1024, xh, 1024, 2048LL * 1024,
      P, 2048, 2048LL * 2048, 1024, nullptr);
  // out = (P @ VT^T)/rowsum + bias  (rowsum on VALU pipe)      512 blocks (2/CU)
  gemm_out<<<dim3(8, 16, 4), 256, 0, stream>>>(
      P, 2048, 2048LL * 2048, VT, 2048, 1024LL * 2048,
      out, 1024, 2048LL * 1024, 2048, bout);
}

// Round 16
// 163.600 us; speedup vs baseline: 1.0632x; 1.0341x over previous
//
#include <hip/hip_runtime.h>
#include <hip/hip_bf16.h>

// ---------------------------------------------------------------------------
// Attention_58248346469030:  out = softmax((x@Wq)(x@Wk)^T * sc) @ (x@Wv) @ Wout + b
// B=4, S=2048, DIM=1024, INNER=1024 (full-dim attention, no head split).
//
// BEST-MEASURED COMPOSITION (= R13 verbatim, 163.9us):
//   ALGEBRAIC FOLD: dots = x@(sc*Wq@Wk^T)@x^T, out = (P@(x@(Wv@Wout)))/l + b
//   prep:  xh = fp16(x); WoutT = W_out^T fp16; prep_gemm64 (reads Wqkv f32
//          directly) -> Wyv [2048][1024] fp16
//   1) yv  = xh @ Wyv^T : y fp16 [8192][1024], v' bf16 -> VT[b][o][t]
//   2) P   = exp(y @ xh^T)  bf16  (pure store epilogue)
//   3) out = (P @ VT^T)/rowsum + bias; rowsum via ones-MFMA on A=P fragments
//      (measured best of three variants: ones-MFMA 163.9 < VALU 169.2 <
//       atomics 173.9)
//   T1 bijective XCD swizzle on all big GEMMs (FETCH 139->33MB).
// ---------------------------------------------------------------------------

typedef short    s16x8 __attribute__((ext_vector_type(8)));
typedef short    s16x4 __attribute__((ext_vector_type(4)));
typedef float    fx4   __attribute__((ext_vector_type(4)));
typedef _Float16 h16x8 __attribute__((ext_vector_type(8)));

__device__ __forceinline__ short f2bs(float f) {            // f32 -> bf16 bits (RNE)
  __hip_bfloat16 h = __float2bfloat16(f);
  short s; __builtin_memcpy(&s, &h, 2); return s;
}
__device__ __forceinline__ short f2hs(float f) {            // f32 -> fp16 bits (RNE)
  _Float16 h = (_Float16)f;
  short s; __builtin_memcpy(&s, &h, 2); return s;
}

__device__ __forceinline__ void gload16(const void* g, void* l) {
  __builtin_amdgcn_global_load_lds(
      (const __attribute__((address_space(1))) void*)g,
      (__attribute__((address_space(3))) void*)l, 16, 0, 0);
}

// T1: bijective XCD-chunked swizzle (grids all %8==0).
template<int GX, int GY>
__device__ __forceinline__ void xcd_map(int& bx, int& by, int& bz) {
  const int glin = ((int)blockIdx.z * GY + (int)blockIdx.y) * GX + (int)blockIdx.x;
  const int nwg  = GX * GY * (int)gridDim.z;
  const int s    = (glin & 7) * (nwg >> 3) + (glin >> 3);
  bx = s % GX;
  const int t = s / GX;
  by = t % GY;
  bz = t / GY;
}

// ---------------- prep kernels ----------------

__global__ void cvt_f32_f16(const float* __restrict__ in, short* __restrict__ out, int n4) {
  int i = blockIdx.x * blockDim.x + threadIdx.x;
  if (i < n4) {
    float4 v = reinterpret_cast<const float4*>(in)[i];
    s16x4 o;
    o.x = f2hs(v.x); o.y = f2hs(v.y); o.z = f2hs(v.z); o.w = f2hs(v.w);
    reinterpret_cast<s16x4*>(out)[i] = o;
  }
}

// WT[n][k] = W[k][n], fp16 out.
__global__ void transpose_w(const float* __restrict__ W, int K, int N,
                            short* __restrict__ WT) {
  __shared__ float tile[32][33];
  int k0 = blockIdx.y * 32, n0 = blockIdx.x * 32;
  int r = threadIdx.x >> 5, c = threadIdx.x & 31;
  for (int rr = r; rr < 32; rr += 8)
    tile[rr][c] = W[(size_t)(k0 + rr) * N + n0 + c];
  __syncthreads();
  for (int rr = r; rr < 32; rr += 8)
    WT[(size_t)(n0 + rr) * K + k0 + c] = f2hs(tile[c][rr]);
}

// Weight-fold GEMMs, 64x64 tiles, K=1024, fp16 MFMA. Reads Wqkv in f32
// (converted in-register during staging); A for the Wvo fold is WoutT fp16.
// by<16 : M^T[e'][e]  = 0.125 * sum_d Wk[e'][d] Wq[e][d]    -> Wyv rows 0-1023
// by>=16: Wvo^T[o][e] =         sum_i WoutT[o][i] Wv[e][i]  -> Wyv rows 1024-2047
__global__ __launch_bounds__(256, 4)
void prep_gemm64(const float* __restrict__ Wqkv, const short* __restrict__ WoutT,
                 short* __restrict__ Wyv) {
  __shared__ __align__(16) short As[64 * 72];
  __shared__ __align__(16) short Bs[64 * 72];

  const bool isM = blockIdx.y < 16;
  const int arow0 = (blockIdx.y & 15) * 64;
  const int crow0 = arow0 + (isM ? 0 : 1024);
  const int bcol = blockIdx.x * 64;
  const float scale = isM ? 0.125f : 1.0f;

  const int t = threadIdx.x;
  const int r = t >> 2;
  const int sc = (t & 3) * 16;
  // A: isM -> Wqkv[arow0+r][1024 + sc + kt] (Wk, f32); else WoutT fp16
  const float* Agf = Wqkv + (size_t)(arow0 + r) * 3072 + 1024 + sc;
  const short* Agh = WoutT + (size_t)(arow0 + r) * 1024 + sc;
  // B: Wqkv[bcol+r][(isM?0:2048) + sc + kt] (Wq | Wv, f32)
  const float* Bgf = Wqkv + (size_t)(bcol + r) * 3072 + (isM ? 0 : 2048) + sc;

  short* Asw = &As[r * 72 + sc];
  short* Bsw = &Bs[r * 72 + sc];

  const int lane = t & 63;
  const int wid  = t >> 6;
  const int wm = wid >> 1, wn = wid & 1;
  const int fr = lane & 15, fg = lane >> 4;

  fx4 acc[2][2] = {};

  for (int kt = 0; kt < 1024; kt += 64) {
    s16x8 ar[2], br[2];
    if (isM) {
#pragma unroll
      for (int c = 0; c < 2; ++c) {
        float4 v0 = *reinterpret_cast<const float4*>(Agf + kt + c * 8);
        float4 v1 = *reinterpret_cast<const float4*>(Agf + kt + c * 8 + 4);
        ar[c][0] = f2hs(v0.x); ar[c][1] = f2hs(v0.y); ar[c][2] = f2hs(v0.z); ar[c][3] = f2hs(v0.w);
        ar[c][4] = f2hs(v1.x); ar[c][5] = f2hs(v1.y); ar[c][6] = f2hs(v1.z); ar[c][7] = f2hs(v1.w);
      }
    } else {
#pragma unroll
      for (int c = 0; c < 2; ++c)
        ar[c] = *reinterpret_cast<const s16x8*>(Agh + kt + c * 8);
    }
#pragma unroll
    for (int c = 0; c < 2; ++c) {
      float4 v0 = *reinterpret_cast<const float4*>(Bgf + kt + c * 8);
      float4 v1 = *reinterpret_cast<const float4*>(Bgf + kt + c * 8 + 4);
      br[c][0] = f2hs(v0.x); br[c][1] = f2hs(v0.y); br[c][2] = f2hs(v0.z); br[c][3] = f2hs(v0.w);
      br[c][4] = f2hs(v1.x); br[c][5] = f2hs(v1.y); br[c][6] = f2hs(v1.z); br[c][7] = f2hs(v1.w);
    }
    __syncthreads();
#pragma unroll
    for (int c = 0; c < 2; ++c) {
      *reinterpret_cast<s16x8*>(Asw + c * 8) = ar[c];
      *reinterpret_cast<s16x8*>(Bsw + c * 8) = br[c];
    }
    __syncthreads();
#pragma unroll
    for (int kk = 0; kk < 64; kk += 32) {
      s16x8 af[2], bf[2];
#pragma unroll
      for (int m = 0; m < 2; ++m)
        af[m] = *reinterpret_cast<const s16x8*>(&As[(wm * 32 + m * 16 + fr) * 72 + kk + fg * 8]);
#pragma unroll
      for (int n = 0; n < 2; ++n)
        bf[n] = *reinterpret_cast<const s16x8*>(&Bs[(wn * 32 + n * 16 + fr) * 72 + kk + fg * 8]);
#pragma unroll
      for (int m = 0; m < 2; ++m)
#pragma unroll
        for (int n = 0; n < 2; ++n)
          acc[m][n] = __builtin_amdgcn_mfma_f32_16x16x32_f16(
              __builtin_bit_cast(h16x8, af[m]), __builtin_bit_cast(h16x8, bf[n]),
              acc[m][n], 0, 0, 0);
    }
  }

  const int row0 = crow0 + wm * 32 + fg * 4;
  const int col0 = bcol + wn * 32 + fr;
#pragma unroll
  for (int m = 0; m < 2; ++m)
#pragma unroll
    for (int j = 0; j < 4; ++j) {
      const int row = row0 + m * 16 + j;
#pragma unroll
      for (int n = 0; n < 2; ++n)
        Wyv[(size_t)row * 1024 + col0 + n * 16] = f2hs(acc[m][n][j] * scale);
    }
}

// ---------------- 256x256 8-wave 4-slot ping-pong GEMM (R8 core + T1) ----------------
// C[M][N] = A[M][K] @ B'[N][K]^T
// EPI: 0 = yv write (cols <1024: y fp16; >=1024: v' bf16 -> VT=Cv2)
//      1 = exp -> bf16 (pure store)
template<int EPI, int DT, int GX, int GY>
__global__ __launch_bounds__(512, 2)
void gemm256(const short* __restrict__ A, int lda, long long bsA,
             const short* __restrict__ B, int ldb, long long bsB,
             void* __restrict__ Cv, int ldc, long long bsC,
             int K, short* __restrict__ Cv2) {
  __shared__ __align__(16) short S[4][16384];

  const int t = threadIdx.x;
  int bx, by, z;
  xcd_map<GX, GY>(bx, by, z);
  A += (size_t)z * bsA;
  B += (size_t)z * bsB;

  const int brow = by * 256;
  const int bcol = bx * 256;

  const int lane = t & 63;
  const int wid  = t >> 6;
  const int wm = wid >> 2;
  const int wn = wid & 3;
  const int fr = lane & 15;
  const int fg = lane >> 4;

  const int l2 = lane >> 2;
  const int gsrc = ((lane & 3) ^ ((lane >> 3) & 3)) * 8;
  const short* Ag0 = A + (size_t)(brow + wid * 32 + l2) * lda + gsrc;
  const short* Ag1 = Ag0 + (size_t)16 * lda;
  const short* Bg0 = B + (size_t)(bcol + wid * 32 + l2) * ldb + gsrc;
  const short* Bg1 = Bg0 + (size_t)16 * ldb;
  const int dA = wid * 1024;
  const int dB = 8192 + wid * 1024;

  const int gq = (fg ^ ((fr >> 1) & 3)) * 8;
  const int aB = (wm * 128 + fr) * 32 + gq;
  const int bB = 8192 + (wn * 64 + fr) * 32 + gq;

  fx4 acc[8][4] = {};
  s16x8 ra[2][8], rb[2][4];
  const int Km32 = K - 32;

  auto MM = [&](s16x8 av, s16x8 bv, fx4 c) -> fx4 {
    if constexpr (DT == 0)
      return __builtin_amdgcn_mfma_f32_16x16x32_f16(
          __builtin_bit_cast(h16x8, av), __builtin_bit_cast(h16x8, bv), c, 0, 0, 0);
    else
      return __builtin_amdgcn_mfma_f32_16x16x32_bf16(av, bv, c, 0, 0, 0);
  };

#pragma unroll
  for (int s = 0; s < 3; ++s) {
    const int kk = s * 32;
    gload16(Ag0 + kk, &S[s][dA]);
    gload16(Ag1 + kk, &S[s][dA + 512]);
    gload16(Bg0 + kk, &S[s][dB]);
    gload16(Bg1 + kk, &S[s][dB + 512]);
  }
  asm volatile("s_waitcnt vmcnt(8)" ::: "memory");
  __builtin_amdgcn_s_barrier();
#pragma unroll
  for (int m = 0; m < 8; ++m)
    ra[0][m] = *reinterpret_cast<const s16x8*>(&S[0][aB + m * 512]);
#pragma unroll
  for (int n = 0; n < 4; ++n)
    rb[0][n] = *reinterpret_cast<const s16x8*>(&S[0][bB + n * 512]);
  int knext = 96;

#define PHASE(SLOT, CUR, NXT)                                                \
  {                                                                          \
    asm volatile("s_waitcnt vmcnt(4)" ::: "memory");                         \
    __builtin_amdgcn_s_barrier();                                            \
    const int kk = knext <= Km32 ? knext : Km32;                             \
    short* D = &S[(SLOT + 3) & 3][0];                                        \
    gload16(Ag0 + kk, D + dA);                                               \
    gload16(Ag1 + kk, D + dA + 512);                                         \
    gload16(Bg0 + kk, D + dB);                                               \
    gload16(Bg1 + kk, D + dB + 512);                                         \
    knext += 32;                                                             \
    const short* Sl = &S[(SLOT + 1) & 3][0];                                 \
    _Pragma("unroll")                                                        \
    for (int m = 0; m < 8; ++m)                                              \
      ra[NXT][m] = *reinterpret_cast<const s16x8*>(&Sl[aB + m * 512]);       \
    _Pragma("unroll")                                                        \
    for (int n = 0; n < 4; ++n)                                              \
      rb[NXT][n] = *reinterpret_cast<const s16x8*>(&Sl[bB + n * 512]);       \
    __builtin_amdgcn_sched_barrier(0);                                       \
    __builtin_amdgcn_s_setprio(1);                                           \
    _Pragma("unroll")                                                        \
    for (int m = 0; m < 8; ++m)                                              \
      _Pragma("unroll")                                                      \
      for (int n = 0; n < 4; ++n)                                            \
        acc[m][n] = MM(ra[CUR][m], rb[CUR][n], acc[m][n]);                   \
    __builtin_amdgcn_s_setprio(0);                                           \
  }

  const int NPH = K >> 5;                // K multiple of 128 -> NPH % 4 == 0
  for (int p = 0; p < NPH; p += 4) {
    PHASE(0, 0, 1) PHASE(1, 1, 0) PHASE(2, 0, 1) PHASE(3, 1, 0)
  }
#undef PHASE
  asm volatile("s_waitcnt vmcnt(0)" ::: "memory");

  const int row0 = brow + wm * 128 + fg * 4;
  const int col0 = bcol + wn * 64 + fr;

  if constexpr (EPI == 0) {
    short* Cb = reinterpret_cast<short*>(Cv);
    if (bcol < 1024) {                    // y columns -> fp16 [8192][1024]
#pragma unroll
      for (int m = 0; m < 8; ++m)
#pragma unroll
        for (int j = 0; j < 4; ++j) {
          const int row = row0 + m * 16 + j;
#pragma unroll
          for (int n = 0; n < 4; ++n)
            Cb[(size_t)row * ldc + col0 + n * 16] = f2hs(acc[m][n][j]);
        }
    } else {                              // v' columns -> bf16 into VT[b][o][t]
#pragma unroll
      for (int m = 0; m < 8; ++m)
#pragma unroll
        for (int j = 0; j < 4; ++j) {
          const int row = row0 + m * 16 + j;
          const int zb = row >> 11, s = row & 2047;
#pragma unroll
          for (int n = 0; n < 4; ++n) {
            const int d = col0 + n * 16 - 1024;
            Cv2[((size_t)(zb << 10) + d) * 2048 + s] = f2bs(acc[m][n][j]);
          }
        }
    }
  } else {
    // P = exp(dots) bf16, pure store (rowsum computed in gemm_out)
    short* Cb = reinterpret_cast<short*>(Cv) + (size_t)z * bsC;
#pragma unroll
    for (int m = 0; m < 8; ++m)
#pragma unroll
      for (int j = 0; j < 4; ++j) {
        const int row = row0 + m * 16 + j;
#pragma unroll
        for (int n = 0; n < 4; ++n)
          Cb[(size_t)row * ldc + col0 + n * 16] =
              f2bs(exp2f(acc[m][n][j] * 1.4426950408889634f));
      }
  }
}

// ---------------- 128x128 R1-core GEMM (out; fused rowsum via ones-MFMA) ----
__global__ __launch_bounds__(256, 2)
void gemm_out(const short* __restrict__ A, int lda, long long bsA,
              const short* __restrict__ B, int ldb, long long bsB,
              float* __restrict__ Cv, int ldc, long long bsC,
              int K, const float* __restrict__ aux) {
  __shared__ __align__(16) short As[128 * 72];
  __shared__ __align__(16) short Bs[128 * 72];

  const int t = threadIdx.x;
  int bx, by, z;
  xcd_map<8, 16>(bx, by, z);
  A += (size_t)z * bsA;
  B += (size_t)z * bsB;

  const int brow = by * 128;
  const int bcol = bx * 128;

  const int srow = t >> 1;
  const int scol = (t & 1) << 5;
  const short* Ag = A + (size_t)(brow + srow) * lda + scol;
  const short* Bg = B + (size_t)(bcol + srow) * ldb + scol;
  short* Asw = &As[srow * 72 + scol];
  short* Bsw = &Bs[srow * 72 + scol];

  const int lane = t & 63;
  const int wid  = t >> 6;
  const int wr = (wid >> 1) * 64;
  const int wc = (wid & 1) * 64;
  const int fr = lane & 15;
  const int fg = lane >> 4;

  fx4 acc[4][4] = {};
  fx4 acc_rs[4] = {};                    // rowsum accumulator (ones-MFMA)
  s16x8 ones;
#pragma unroll
  for (int i = 0; i < 8; ++i) ones[i] = (short)0x3F80;   // bf16 1.0

  for (int kt = 0; kt < K; kt += 64) {
    s16x8 ar[4], br[4];
#pragma unroll
    for (int c = 0; c < 4; ++c) ar[c] = *reinterpret_cast<const s16x8*>(Ag + kt + c * 8);
#pragma unroll
    for (int c = 0; c < 4; ++c) br[c] = *reinterpret_cast<const s16x8*>(Bg + kt + c * 8);
    __syncthreads();
#pragma unroll
    for (int c = 0; c < 4; ++c) *reinterpret_cast<s16x8*>(Asw + c * 8) = ar[c];
#pragma unroll
    for (int c = 0; c < 4; ++c) *reinterpret_cast<s16x8*>(Bsw + c * 8) = br[c];
    __syncthreads();

#pragma unroll
    for (int kk = 0; kk < 64; kk += 32) {
      s16x8 af[4], bfv[4];
#pragma unroll
      for (int m = 0; m < 4; ++m)
        af[m] = *reinterpret_cast<const s16x8*>(&As[(wr + m * 16 + fr) * 72 + kk + fg * 8]);
#pragma unroll
      for (int n = 0; n < 4; ++n)
        bfv[n] = *reinterpret_cast<const s16x8*>(&Bs[(wc + n * 16 + fr) * 72 + kk + fg * 8]);
#pragma unroll
      for (int m = 0; m < 4; ++m) {
#pragma unroll
        for (int n = 0; n < 4; ++n)
          acc[m][n] = __builtin_amdgcn_mfma_f32_16x16x32_bf16(af[m], bfv[n], acc[m][n], 0, 0, 0);
        acc_rs[m] = __builtin_amdgcn_mfma_f32_16x16x32_bf16(af[m], ones, acc_rs[m], 0, 0, 0);
      }
    }
  }

  // D layout: row = fg*4 + j, col = fr. acc_rs[m][j] = rowsum(row0 + m*16 + j)
  const int row0 = brow + wr + fg * 4;
  const int col0 = bcol + wc + fr;
#pragma unroll
  for (int m = 0; m < 4; ++m)
#pragma unroll
    for (int j = 0; j < 4; ++j) {
      const int row = row0 + m * 16 + j;
      const float rcp = 1.0f / acc_rs[m][j];
#pragma unroll
      for (int n = 0; n < 4; ++n) {
        const int col = col0 + n * 16;
        Cv[(size_t)z * bsC + (size_t)row * ldc + col] = acc[m][n][j] * rcp + aux[col];
      }
    }
}

// ---------------- launch ----------------

extern "C" void kernel_launch(void* const* d_in, const int* in_sizes, int n_in,
                              void* d_out, int out_size, void* d_ws, size_t ws_size,
                              hipStream_t stream) {
  const float* x    = (const float*)d_in[0];   // [4,2048,1024]
  const float* Wqkv = (const float*)d_in[1];   // [1024,3072]
  const float* Wout = (const float*)d_in[2];   // [1024,1024]
  const float* bout = (const float*)d_in[3];   // [1024]
  float* out = (float*)d_out;                  // [4,2048,1024] fp32

  // workspace layout (bytes)
  char* ws = (char*)d_ws;
  short* xh    = (short*)(ws + 0);             //  16777216  fp16 x [8192][1024]
  short* WoutT = (short*)(ws + 16777216);      //   2097152  fp16 W_out^T [1024][1024]
  short* Wyv   = (short*)(ws + 18874368);      //   4194304  fp16 [M^T; Wvo^T] [2048][1024]
  short* y     = (short*)(ws + 23068672);      //  16777216  fp16 [8192][1024]
  short* VT    = (short*)(ws + 39845888);      //  16777216  bf16 v' [4][1024][2048]
  short* P     = (short*)(ws + 56623104);      //  33554432  bf16 [4][2048][2048]
  if (ws_size < 90177536) return;              // insufficient scratch -> visible failure

  cvt_f32_f16<<<8192, 256, 0, stream>>>(x, xh, 8388608 / 4);
  transpose_w<<<dim3(32, 32), 256, 0, stream>>>(Wout, 1024, 1024, WoutT);
  // M^T (scale folded) and Wvo^T -> Wyv (reads Wqkv f32 directly)
  prep_gemm64<<<dim3(16, 32), 256, 0, stream>>>(Wqkv, WoutT, Wyv);

  // yv = xh @ Wyv^T  (y cols 0-1023 -> y; v' -> VT)           256 blocks (1/CU)
  gemm256<0, 0, 8, 32><<<dim3(8, 32, 1), 512, 0, stream>>>(
      xh, 1024, 0, Wyv, 1024, 0, y, 1024, 0, 1024, VT);
  // P = exp(y @ xh^T)                                          256 blocks (1/CU)
  gemm256<1, 0, 8, 8><<<dim3(8, 8, 4), 512, 0, stream>>>(
      y, 1024, 2048LL * 1024, xh, 1024, 2048LL * 1024,
      P, 2048, 2048LL * 2048, 1024, nullptr);
  // out = (P @ VT^T)/rowsum + bias  (rowsum fused via ones-MFMA)  512 blocks
  gemm_out<<<dim3(8, 16, 4), 256, 0, stream>>>(
      P, 2048, 2048LL * 2048, VT, 2048, 1024LL * 2048,
      out, 1024, 2048LL * 1024, 2048, bout);
}